// Round 1
// baseline (1763.574 us; speedup 1.0000x reference)
//
#include <hip/hip_runtime.h>
#include <hip/hip_bf16.h>

#define NROWS 500000
#define DIM   256
#define BSEG  16384
#define TM    64
#define BK    16

// ws layout (floats):
//   [0,            BSEG*DIM)   local_rep
//   [BSEG*DIM,   2*BSEG*DIM)   global_rep
//   [2*BSEG*DIM, 3*BSEG*DIM)   H1 = local_rep@W1 + b1

__device__ __forceinline__ float fast_sigmoid(float z) {
  return 1.0f / (1.0f + __expf(-z));
}

__global__ __launch_bounds__(1024) void k_zero(float* __restrict__ p, int n4) {
  int i = blockIdx.x * blockDim.x + threadIdx.x;
  if (i < n4) ((float4*)p)[i] = make_float4(0.f, 0.f, 0.f, 0.f);
}

// local_rep[s][c] = sum_{r in seg s} x[r][c] * mask[r]
// batch is sorted: per-block running accumulator, atomic flush on seg change.
__global__ __launch_bounds__(256) void k_seg_local(
    const float* __restrict__ x, const int* __restrict__ batch,
    const float* __restrict__ mask, float* __restrict__ local_rep,
    int rows_per_block)
{
  const int col = threadIdx.x;
  int r0 = blockIdx.x * rows_per_block;
  int r1 = min(NROWS, r0 + rows_per_block);
  if (r0 >= r1) return;
  float acc = 0.f;
  int cur = batch[r0];
  for (int r = r0; r < r1; ++r) {
    int s = batch[r];
    float xv = x[r * DIM + col];
    float mv = mask[r];
    if (s != cur) {
      atomicAdd(&local_rep[cur * DIM + col], acc);
      acc = 0.f; cur = s;
    }
    acc = fmaf(xv, mv, acc);
  }
  atomicAdd(&local_rep[cur * DIM + col], acc);
}

// H1 = local_rep @ W1 + b1   [BSEG x DIM]
__global__ __launch_bounds__(256) void k_gemm_h1(
    const float* __restrict__ A, const float* __restrict__ W,
    const float* __restrict__ bias, float* __restrict__ H1)
{
  __shared__ float aT[BK][TM];
  __shared__ float bs[BK][DIM];
  const int tid = threadIdx.x;
  const int tc = tid & 31, tr = tid >> 5;
  const int row0 = blockIdx.x * TM;
  float acc[8][8] = {};

  const int m  = tid >> 2;
  const int kq = (tid & 3) * 4;
  const int kb = tid >> 4;
  const int cb = (tid & 15) * 16;

  for (int kk = 0; kk < DIM; kk += BK) {
    float4 av = *(const float4*)&A[(row0 + m) * DIM + kk + kq];
    float4 bv0 = *(const float4*)&W[(kk + kb) * DIM + cb + 0];
    float4 bv1 = *(const float4*)&W[(kk + kb) * DIM + cb + 4];
    float4 bv2 = *(const float4*)&W[(kk + kb) * DIM + cb + 8];
    float4 bv3 = *(const float4*)&W[(kk + kb) * DIM + cb + 12];
    __syncthreads();
    aT[kq + 0][m] = av.x; aT[kq + 1][m] = av.y;
    aT[kq + 2][m] = av.z; aT[kq + 3][m] = av.w;
    *(float4*)&bs[kb][cb + 0]  = bv0;
    *(float4*)&bs[kb][cb + 4]  = bv1;
    *(float4*)&bs[kb][cb + 8]  = bv2;
    *(float4*)&bs[kb][cb + 12] = bv3;
    __syncthreads();
#pragma unroll
    for (int k = 0; k < BK; ++k) {
      float a8[8], b8[8];
      *(float4*)&a8[0] = *(const float4*)&aT[k][tr * 8];
      *(float4*)&a8[4] = *(const float4*)&aT[k][tr * 8 + 4];
      *(float4*)&b8[0] = *(const float4*)&bs[k][tc * 8];
      *(float4*)&b8[4] = *(const float4*)&bs[k][tc * 8 + 4];
#pragma unroll
      for (int i = 0; i < 8; ++i)
#pragma unroll
        for (int j = 0; j < 8; ++j)
          acc[i][j] = fmaf(a8[i], b8[j], acc[i][j]);
    }
  }
  float bias8[8];
  *(float4*)&bias8[0] = *(const float4*)&bias[tc * 8];
  *(float4*)&bias8[4] = *(const float4*)&bias[tc * 8 + 4];
#pragma unroll
  for (int i = 0; i < 8; ++i) {
    int row = row0 + tr * 8 + i;
    float o[8];
#pragma unroll
    for (int j = 0; j < 8; ++j) o[j] = acc[i][j] + bias8[j];
    *(float4*)&H1[row * DIM + tc * 8]     = *(float4*)&o[0];
    *(float4*)&H1[row * DIM + tc * 8 + 4] = *(float4*)&o[4];
  }
}

// Fused: z = x@W2 + b2 + H1[batch]; att = sigmoid(z)@w3;
// global_rep = segsum(x * att)
__global__ __launch_bounds__(256) void k_fused_main(
    const float* __restrict__ x, const int* __restrict__ batch,
    const float* __restrict__ W2, const float* __restrict__ b2,
    const float* __restrict__ w3, const float* __restrict__ H1,
    float* __restrict__ global_rep)
{
  __shared__ float aT[BK][TM];
  __shared__ float bs[BK][DIM];
  __shared__ int   seg_s[TM];
  __shared__ float att_s[TM];
  const int tid = threadIdx.x;
  const int tc = tid & 31, tr = tid >> 5;
  const int row0 = blockIdx.x * TM;

  if (tid < TM) {
    int row = row0 + tid;
    seg_s[tid] = batch[min(row, NROWS - 1)];
  }

  const int m  = tid >> 2;
  const int kq = (tid & 3) * 4;
  const int kb = tid >> 4;
  const int cb = (tid & 15) * 16;

  float acc[8][8] = {};
  for (int kk = 0; kk < DIM; kk += BK) {
    float4 av = make_float4(0.f, 0.f, 0.f, 0.f);
    int row = row0 + m;
    if (row < NROWS) av = *(const float4*)&x[row * DIM + kk + kq];
    float4 bv0 = *(const float4*)&W2[(kk + kb) * DIM + cb + 0];
    float4 bv1 = *(const float4*)&W2[(kk + kb) * DIM + cb + 4];
    float4 bv2 = *(const float4*)&W2[(kk + kb) * DIM + cb + 8];
    float4 bv3 = *(const float4*)&W2[(kk + kb) * DIM + cb + 12];
    __syncthreads();
    aT[kq + 0][m] = av.x; aT[kq + 1][m] = av.y;
    aT[kq + 2][m] = av.z; aT[kq + 3][m] = av.w;
    *(float4*)&bs[kb][cb + 0]  = bv0;
    *(float4*)&bs[kb][cb + 4]  = bv1;
    *(float4*)&bs[kb][cb + 8]  = bv2;
    *(float4*)&bs[kb][cb + 12] = bv3;
    __syncthreads();
#pragma unroll
    for (int k = 0; k < BK; ++k) {
      float a8[8], b8[8];
      *(float4*)&a8[0] = *(const float4*)&aT[k][tr * 8];
      *(float4*)&a8[4] = *(const float4*)&aT[k][tr * 8 + 4];
      *(float4*)&b8[0] = *(const float4*)&bs[k][tc * 8];
      *(float4*)&b8[4] = *(const float4*)&bs[k][tc * 8 + 4];
#pragma unroll
      for (int i = 0; i < 8; ++i)
#pragma unroll
        for (int j = 0; j < 8; ++j)
          acc[i][j] = fmaf(a8[i], b8[j], acc[i][j]);
    }
  }

  // epilogue: z -> sigmoid -> dot w3 -> att per row
  float w3v[8], b2v[8];
  *(float4*)&w3v[0] = *(const float4*)&w3[tc * 8];
  *(float4*)&w3v[4] = *(const float4*)&w3[tc * 8 + 4];
  *(float4*)&b2v[0] = *(const float4*)&b2[tc * 8];
  *(float4*)&b2v[4] = *(const float4*)&b2[tc * 8 + 4];
  float part[8];
#pragma unroll
  for (int i = 0; i < 8; ++i) {
    int seg = seg_s[tr * 8 + i];
    const float* h1r = &H1[seg * DIM + tc * 8];
    float h[8];
    *(float4*)&h[0] = *(const float4*)&h1r[0];
    *(float4*)&h[4] = *(const float4*)&h1r[4];
    float p = 0.f;
#pragma unroll
    for (int j = 0; j < 8; ++j) {
      float z = acc[i][j] + h[j] + b2v[j];
      p = fmaf(fast_sigmoid(z), w3v[j], p);
    }
    part[i] = p;
  }
  // reduce across the 32 lanes sharing this tr (stays within 32-lane half-wave)
#pragma unroll
  for (int off = 1; off < 32; off <<= 1)
#pragma unroll
    for (int i = 0; i < 8; ++i)
      part[i] += __shfl_xor(part[i], off, 64);
  if (tc == 0) {
#pragma unroll
    for (int i = 0; i < 8; ++i) att_s[tr * 8 + i] = part[i];
  }
  __syncthreads();

  // phase 2: weighted segment sum of x*att into global_rep
  const int col = tid;
  float acc2 = 0.f;
  int cur = seg_s[0];
  int rmax = min(TM, NROWS - row0);
  for (int r = 0; r < rmax; ++r) {
    int s = seg_s[r];
    float xv = x[(row0 + r) * DIM + col];
    float av = att_s[r];
    if (s != cur) {
      atomicAdd(&global_rep[cur * DIM + col], acc2);
      acc2 = 0.f; cur = s;
    }
    acc2 = fmaf(xv, av, acc2);
  }
  atomicAdd(&global_rep[cur * DIM + col], acc2);
}

// out = local_rep @ W4[0:256] + global_rep @ W4[256:512] + b4
__global__ __launch_bounds__(256) void k_gemm_out(
    const float* __restrict__ local_rep, const float* __restrict__ global_rep,
    const float* __restrict__ W4, const float* __restrict__ b4,
    float* __restrict__ out)
{
  __shared__ float aT[BK][TM];
  __shared__ float bs[BK][DIM];
  const int tid = threadIdx.x;
  const int tc = tid & 31, tr = tid >> 5;
  const int row0 = blockIdx.x * TM;
  float acc[8][8] = {};

  const int m  = tid >> 2;
  const int kq = (tid & 3) * 4;
  const int kb = tid >> 4;
  const int cb = (tid & 15) * 16;

  for (int pass = 0; pass < 2; ++pass) {
    const float* A = pass ? global_rep : local_rep;
    const float* W = W4 + pass * DIM * DIM;
    for (int kk = 0; kk < DIM; kk += BK) {
      float4 av = *(const float4*)&A[(row0 + m) * DIM + kk + kq];
      float4 bv0 = *(const float4*)&W[(kk + kb) * DIM + cb + 0];
      float4 bv1 = *(const float4*)&W[(kk + kb) * DIM + cb + 4];
      float4 bv2 = *(const float4*)&W[(kk + kb) * DIM + cb + 8];
      float4 bv3 = *(const float4*)&W[(kk + kb) * DIM + cb + 12];
      __syncthreads();
      aT[kq + 0][m] = av.x; aT[kq + 1][m] = av.y;
      aT[kq + 2][m] = av.z; aT[kq + 3][m] = av.w;
      *(float4*)&bs[kb][cb + 0]  = bv0;
      *(float4*)&bs[kb][cb + 4]  = bv1;
      *(float4*)&bs[kb][cb + 8]  = bv2;
      *(float4*)&bs[kb][cb + 12] = bv3;
      __syncthreads();
#pragma unroll
      for (int k = 0; k < BK; ++k) {
        float a8[8], b8[8];
        *(float4*)&a8[0] = *(const float4*)&aT[k][tr * 8];
        *(float4*)&a8[4] = *(const float4*)&aT[k][tr * 8 + 4];
        *(float4*)&b8[0] = *(const float4*)&bs[k][tc * 8];
        *(float4*)&b8[4] = *(const float4*)&bs[k][tc * 8 + 4];
#pragma unroll
        for (int i = 0; i < 8; ++i)
#pragma unroll
          for (int j = 0; j < 8; ++j)
            acc[i][j] = fmaf(a8[i], b8[j], acc[i][j]);
      }
    }
  }
  float bias8[8];
  *(float4*)&bias8[0] = *(const float4*)&b4[tc * 8];
  *(float4*)&bias8[4] = *(const float4*)&b4[tc * 8 + 4];
#pragma unroll
  for (int i = 0; i < 8; ++i) {
    int row = row0 + tr * 8 + i;
    float o[8];
#pragma unroll
    for (int j = 0; j < 8; ++j) o[j] = acc[i][j] + bias8[j];
    *(float4*)&out[row * DIM + tc * 8]     = *(float4*)&o[0];
    *(float4*)&out[row * DIM + tc * 8 + 4] = *(float4*)&o[4];
  }
}

extern "C" void kernel_launch(void* const* d_in, const int* in_sizes, int n_in,
                              void* d_out, int out_size, void* d_ws, size_t ws_size,
                              hipStream_t stream) {
  (void)in_sizes; (void)n_in; (void)out_size; (void)ws_size;
  const float* x    = (const float*)d_in[0];
  const int*   batch= (const int*)d_in[1];
  const float* mask = (const float*)d_in[2];
  // d_in[3] = num_segments (known: 16384)
  const float* W1 = (const float*)d_in[4];
  const float* b1 = (const float*)d_in[5];
  const float* W2 = (const float*)d_in[6];
  const float* b2 = (const float*)d_in[7];
  const float* w3 = (const float*)d_in[8];
  const float* W4 = (const float*)d_in[9];
  const float* b4 = (const float*)d_in[10];
  float* out = (float*)d_out;

  float* local_rep  = (float*)d_ws;
  float* global_rep = local_rep + (size_t)BSEG * DIM;
  float* H1         = global_rep + (size_t)BSEG * DIM;

  // zero local_rep + global_rep (2 * 16384 * 256 floats = 2M float4)
  int n4 = 2 * BSEG * DIM / 4;
  hipLaunchKernelGGL(k_zero, dim3((n4 + 1023) / 1024), dim3(1024), 0, stream,
                     local_rep, n4);

  const int SEG_BLOCKS = 1024;
  int rpb = (NROWS + SEG_BLOCKS - 1) / SEG_BLOCKS;
  hipLaunchKernelGGL(k_seg_local, dim3(SEG_BLOCKS), dim3(256), 0, stream,
                     x, batch, mask, local_rep, rpb);

  hipLaunchKernelGGL(k_gemm_h1, dim3(BSEG / TM), dim3(256), 0, stream,
                     local_rep, W1, b1, H1);

  hipLaunchKernelGGL(k_fused_main, dim3((NROWS + TM - 1) / TM), dim3(256), 0, stream,
                     x, batch, W2, b2, w3, H1, global_rep);

  hipLaunchKernelGGL(k_gemm_out, dim3(BSEG / TM), dim3(256), 0, stream,
                     local_rep, global_rep, W4, b4, out);
}

// Round 3
// 991.059 us; speedup vs baseline: 1.7795x; 1.7795x over previous
//
#include <hip/hip_runtime.h>
#include <hip/hip_bf16.h>

#define NROWS 500000
#define DIM   256
#define BSEG  16384
#define LDSP  264   // LDS pitch in bf16 elems: 256 + 8 pad -> 2-way-free ds_read_b128

typedef __attribute__((ext_vector_type(8))) short short8;
typedef __attribute__((ext_vector_type(4))) float floatx4;

// ws layout (bytes):
//   [0,        16M)  local_rep  f32 [BSEG][DIM]
//   [16M,      32M)  global_rep f32 [BSEG][DIM]
//   [32M,      40M)  H1         bf16 [BSEG][DIM]
//   [40M,        +128K) W1t bf16 k-tiled
//   [40M+128K,  +128K) W2t bf16 k-tiled
//   [40M+256K,  +256K) W4t bf16 k-tiled (K=512)

__device__ __forceinline__ unsigned short f2bf(float f) {
  unsigned u = __float_as_uint(f);
  unsigned r = u + 0x7fffu + ((u >> 16) & 1u);  // RNE
  return (unsigned short)(r >> 16);
}
__device__ __forceinline__ float bf2f(short s) {
  return __uint_as_float(((unsigned)(unsigned short)s) << 16);
}
__device__ __forceinline__ float fast_sigmoid(float z) {
  return 1.0f / (1.0f + __expf(-z));
}

__global__ __launch_bounds__(1024) void k_zero(float* __restrict__ p, int n4) {
  int i = blockIdx.x * blockDim.x + threadIdx.x;
  if (i < n4) ((float4*)p)[i] = make_float4(0.f, 0.f, 0.f, 0.f);
}

// Wt[kt][n][kk] = W[kt*32+kk][n]  (bf16), kt-tile size 32
__global__ __launch_bounds__(256) void k_convert_wt(
    const float* __restrict__ W, short* __restrict__ out, int K)
{
  int idx = blockIdx.x * blockDim.x + threadIdx.x;  // idx = kt*256 + n
  int kt = idx >> 8, n = idx & 255;
  if (kt * 32 >= K) return;
  short tmp[32];
#pragma unroll
  for (int kk = 0; kk < 32; ++kk)
    tmp[kk] = (short)f2bf(W[(size_t)(kt * 32 + kk) * DIM + n]);
#pragma unroll
  for (int kk = 0; kk < 32; kk += 4)
    *(short4*)&out[(size_t)idx * 32 + kk] = *(short4*)&tmp[kk];
}

// local_rep[s][c] = sum_{r in seg s} x[r][c] * mask[r]; batch sorted.
__global__ __launch_bounds__(256) void k_seg_local(
    const float* __restrict__ x, const int* __restrict__ batch,
    const float* __restrict__ mask, float* __restrict__ local_rep,
    int rows_per_block)
{
  const int col = threadIdx.x;
  int r0 = blockIdx.x * rows_per_block;
  int r1 = min(NROWS, r0 + rows_per_block);
  if (r0 >= r1) return;
  float acc = 0.f;
  int cur = batch[r0];
  int r = r0;
  for (; r + 4 <= r1; r += 4) {
    float xv0 = x[(size_t)(r + 0) * DIM + col];
    float xv1 = x[(size_t)(r + 1) * DIM + col];
    float xv2 = x[(size_t)(r + 2) * DIM + col];
    float xv3 = x[(size_t)(r + 3) * DIM + col];
    int s0 = batch[r], s1 = batch[r + 1], s2 = batch[r + 2], s3 = batch[r + 3];
    float m0 = mask[r], m1 = mask[r + 1], m2 = mask[r + 2], m3 = mask[r + 3];
    if (s0 != cur) { atomicAdd(&local_rep[(size_t)cur * DIM + col], acc); acc = 0.f; cur = s0; }
    acc = fmaf(xv0, m0, acc);
    if (s1 != cur) { atomicAdd(&local_rep[(size_t)cur * DIM + col], acc); acc = 0.f; cur = s1; }
    acc = fmaf(xv1, m1, acc);
    if (s2 != cur) { atomicAdd(&local_rep[(size_t)cur * DIM + col], acc); acc = 0.f; cur = s2; }
    acc = fmaf(xv2, m2, acc);
    if (s3 != cur) { atomicAdd(&local_rep[(size_t)cur * DIM + col], acc); acc = 0.f; cur = s3; }
    acc = fmaf(xv3, m3, acc);
  }
  for (; r < r1; ++r) {
    int s = batch[r];
    float xv = x[(size_t)r * DIM + col];
    float mv = mask[r];
    if (s != cur) { atomicAdd(&local_rep[(size_t)cur * DIM + col], acc); acc = 0.f; cur = s; }
    acc = fmaf(xv, mv, acc);
  }
  atomicAdd(&local_rep[(size_t)cur * DIM + col], acc);
}

// stage 64x256 fp32 tile -> bf16 LDS (pitch LDSP), rows clamped to maxrow
__device__ __forceinline__ void stage_tile(const float* __restrict__ A, int row0,
                                           int maxrow, short* xs, int tid)
{
#pragma unroll
  for (int it = 0; it < 16; ++it) {
    int linear = it * 256 + tid;
    int r = linear >> 6;      // 64 float4 per row
    int c4 = linear & 63;
    int row = min(row0 + r, maxrow);
    float4 v = *(const float4*)&A[(size_t)row * DIM + c4 * 4];
    short4 o;
    o.x = (short)f2bf(v.x); o.y = (short)f2bf(v.y);
    o.z = (short)f2bf(v.z); o.w = (short)f2bf(v.w);
    *(short4*)&xs[r * LDSP + c4 * 4] = o;
  }
}

// K=256 MFMA pass: acc += xs(64x256 bf16) @ Wt(k-tiled bf16, cols 256)
__device__ __forceinline__ void mfma_pass(const short* xs, const short* __restrict__ Wt,
                                          floatx4 acc[4][4], int lane15, int quad, int n0)
{
  for (int kt = 0; kt < 8; ++kt) {
    short8 bfr[4], afr[4];
#pragma unroll
    for (int jn = 0; jn < 4; ++jn)
      bfr[jn] = *(const short8*)&Wt[(size_t)kt * 8192 + (n0 + jn * 16 + lane15) * 32 + quad * 8];
#pragma unroll
    for (int i = 0; i < 4; ++i)
      afr[i] = *(const short8*)&xs[(i * 16 + lane15) * LDSP + kt * 32 + quad * 8];
#pragma unroll
    for (int i = 0; i < 4; ++i)
#pragma unroll
      for (int jn = 0; jn < 4; ++jn)
        acc[i][jn] = __builtin_amdgcn_mfma_f32_16x16x32_bf16(afr[i], bfr[jn], acc[i][jn], 0, 0, 0);
  }
}

// H1 = bf16(local_rep @ W1 + b1)
__global__ __launch_bounds__(256) void k_h1_mfma(
    const float* __restrict__ A, const short* __restrict__ Wt,
    const float* __restrict__ bias, short* __restrict__ H1bf)
{
  __shared__ short xs[64 * LDSP];
  const int tid = threadIdx.x;
  const int row0 = blockIdx.x * 64;
  stage_tile(A, row0, BSEG - 1, xs, tid);
  __syncthreads();
  const int lane = tid & 63, wave = tid >> 6;
  const int lane15 = lane & 15, quad = lane >> 4;
  const int n0 = wave * 64;
  floatx4 acc[4][4];
#pragma unroll
  for (int i = 0; i < 4; ++i)
#pragma unroll
    for (int j = 0; j < 4; ++j) acc[i][j] = (floatx4)0.f;
  mfma_pass(xs, Wt, acc, lane15, quad, n0);
#pragma unroll
  for (int i = 0; i < 4; ++i)
#pragma unroll
    for (int jn = 0; jn < 4; ++jn) {
      int col = n0 + jn * 16 + lane15;
      float bv = bias[col];
#pragma unroll
      for (int r = 0; r < 4; ++r) {
        int row = row0 + i * 16 + quad * 4 + r;
        H1bf[(size_t)row * DIM + col] = (short)f2bf(acc[i][jn][r] + bv);
      }
    }
}

// Fused: z = x@W2 + b2 + H1[batch]; att = sigmoid(z)@w3; global_rep += segsum(x*att)
__global__ __launch_bounds__(256) void k_fused_main(
    const float* __restrict__ x, const int* __restrict__ batch,
    const short* __restrict__ W2t, const float* __restrict__ b2,
    const float* __restrict__ w3, const short* __restrict__ H1bf,
    float* __restrict__ global_rep)
{
  __shared__ short xs[64 * LDSP];
  __shared__ int   seg_s[64];
  __shared__ float att_s[64];
  const int tid = threadIdx.x;
  const int row0 = blockIdx.x * 64;

  stage_tile(x, row0, NROWS - 1, xs, tid);
  if (tid < 64) {
    seg_s[tid] = batch[min(row0 + tid, NROWS - 1)];
    att_s[tid] = 0.f;
  }
  __syncthreads();

  const int lane = tid & 63, wave = tid >> 6;
  const int lane15 = lane & 15, quad = lane >> 4;
  const int n0 = wave * 64;
  floatx4 acc[4][4];
#pragma unroll
  for (int i = 0; i < 4; ++i)
#pragma unroll
    for (int j = 0; j < 4; ++j) acc[i][j] = (floatx4)0.f;
  mfma_pass(xs, W2t, acc, lane15, quad, n0);

  // epilogue: z -> sigmoid -> dot w3 -> att per row
  float b2v[4], w3v[4];
#pragma unroll
  for (int jn = 0; jn < 4; ++jn) {
    int col = n0 + jn * 16 + lane15;
    b2v[jn] = b2[col];
    w3v[jn] = w3[col];
  }
  float part[4][4];
#pragma unroll
  for (int i = 0; i < 4; ++i)
#pragma unroll
    for (int r = 0; r < 4; ++r) {
      int rl = i * 16 + quad * 4 + r;
      int seg = seg_s[rl];
      float p = 0.f;
#pragma unroll
      for (int jn = 0; jn < 4; ++jn) {
        int col = n0 + jn * 16 + lane15;
        float h = bf2f(H1bf[(size_t)seg * DIM + col]);
        float z = acc[i][jn][r] + h + b2v[jn];
        p = fmaf(fast_sigmoid(z), w3v[jn], p);
      }
      part[i][r] = p;
    }
  // reduce over the 16 lanes (cols) of each quad
#pragma unroll
  for (int off = 1; off < 16; off <<= 1)
#pragma unroll
    for (int i = 0; i < 4; ++i)
#pragma unroll
      for (int r = 0; r < 4; ++r)
        part[i][r] += __shfl_xor(part[i][r], off, 64);
  if (lane15 == 0) {
#pragma unroll
    for (int i = 0; i < 4; ++i)
#pragma unroll
      for (int r = 0; r < 4; ++r)
        atomicAdd(&att_s[i * 16 + quad * 4 + r], part[i][r]);
  }
  __syncthreads();

  // phase 2: weighted segsum of x*att from LDS (bf16 x)
  const int col = tid;
  const int rmax = min(64, NROWS - row0);
  float acc2 = 0.f;
  int cur = seg_s[0];
  for (int r = 0; r < rmax; ++r) {
    int s = seg_s[r];
    float xv = bf2f(xs[r * LDSP + col]);
    float av = att_s[r];
    if (s != cur) {
      atomicAdd(&global_rep[(size_t)cur * DIM + col], acc2);
      acc2 = 0.f; cur = s;
    }
    acc2 = fmaf(xv, av, acc2);
  }
  atomicAdd(&global_rep[(size_t)cur * DIM + col], acc2);
}

// out = local_rep @ W4[0:256] + global_rep @ W4[256:512] + b4
__global__ __launch_bounds__(256) void k_out_mfma(
    const float* __restrict__ local_rep, const float* __restrict__ global_rep,
    const short* __restrict__ W4t, const float* __restrict__ b4,
    float* __restrict__ out)
{
  __shared__ short xs[64 * LDSP];
  const int tid = threadIdx.x;
  const int row0 = blockIdx.x * 64;
  const int lane = tid & 63, wave = tid >> 6;
  const int lane15 = lane & 15, quad = lane >> 4;
  const int n0 = wave * 64;
  floatx4 acc[4][4];
#pragma unroll
  for (int i = 0; i < 4; ++i)
#pragma unroll
    for (int j = 0; j < 4; ++j) acc[i][j] = (floatx4)0.f;

  stage_tile(local_rep, row0, BSEG - 1, xs, tid);
  __syncthreads();
  mfma_pass(xs, W4t, acc, lane15, quad, n0);
  __syncthreads();
  stage_tile(global_rep, row0, BSEG - 1, xs, tid);
  __syncthreads();
  mfma_pass(xs, W4t + (size_t)8 * 8192, acc, lane15, quad, n0);

#pragma unroll
  for (int i = 0; i < 4; ++i)
#pragma unroll
    for (int jn = 0; jn < 4; ++jn) {
      int col = n0 + jn * 16 + lane15;
      float bv = b4[col];
#pragma unroll
      for (int r = 0; r < 4; ++r) {
        int row = row0 + i * 16 + quad * 4 + r;
        out[(size_t)row * DIM + col] = acc[i][jn][r] + bv;
      }
    }
}

extern "C" void kernel_launch(void* const* d_in, const int* in_sizes, int n_in,
                              void* d_out, int out_size, void* d_ws, size_t ws_size,
                              hipStream_t stream) {
  (void)in_sizes; (void)n_in; (void)out_size; (void)ws_size;
  const float* x    = (const float*)d_in[0];
  const int*   batch= (const int*)d_in[1];
  const float* mask = (const float*)d_in[2];
  const float* W1 = (const float*)d_in[4];
  const float* b1 = (const float*)d_in[5];
  const float* W2 = (const float*)d_in[6];
  const float* b2 = (const float*)d_in[7];
  const float* w3 = (const float*)d_in[8];
  const float* W4 = (const float*)d_in[9];
  const float* b4 = (const float*)d_in[10];
  float* out = (float*)d_out;

  char* base = (char*)d_ws;
  float* local_rep  = (float*)(base);
  float* global_rep = (float*)(base + (size_t)16 * 1024 * 1024);
  short* H1bf       = (short*)(base + (size_t)32 * 1024 * 1024);
  short* W1t        = (short*)(base + (size_t)40 * 1024 * 1024);
  short* W2t        = (short*)(base + (size_t)40 * 1024 * 1024 + 128 * 1024);
  short* W4t        = (short*)(base + (size_t)40 * 1024 * 1024 + 256 * 1024);

  // zero local_rep + global_rep
  int n4 = 2 * BSEG * DIM / 4;
  hipLaunchKernelGGL(k_zero, dim3(n4 / 1024), dim3(1024), 0, stream, local_rep, n4);

  // weight conversions (independent of segsum)
  hipLaunchKernelGGL(k_convert_wt, dim3(8),  dim3(256), 0, stream, W1, W1t, 256);
  hipLaunchKernelGGL(k_convert_wt, dim3(8),  dim3(256), 0, stream, W2, W2t, 256);
  hipLaunchKernelGGL(k_convert_wt, dim3(16), dim3(256), 0, stream, W4, W4t, 512);

  const int SEG_BLOCKS = 2048;
  int rpb = (NROWS + SEG_BLOCKS - 1) / SEG_BLOCKS;
  hipLaunchKernelGGL(k_seg_local, dim3(SEG_BLOCKS), dim3(256), 0, stream,
                     x, batch, mask, local_rep, rpb);

  hipLaunchKernelGGL(k_h1_mfma, dim3(BSEG / 64), dim3(256), 0, stream,
                     local_rep, W1t, b1, H1bf);

  hipLaunchKernelGGL(k_fused_main, dim3((NROWS + 63) / 64), dim3(256), 0, stream,
                     x, batch, W2t, b2, w3, H1bf, global_rep);

  hipLaunchKernelGGL(k_out_mfma, dim3(BSEG / 64), dim3(256), 0, stream,
                     local_rep, global_rep, W4t, b4, out);
}